// Round 14
// baseline (498.637 us; speedup 1.0000x reference)
//
#include <hip/hip_runtime.h>
#include <math.h>

#define NN 9
#define RR 128
#define FF 512
#define LL 2
#define GPB 7      // graphs per block (64 rows; 63 used)
#define ROWS 63

typedef __attribute__((ext_vector_type(8))) short bf16x8;  // 8 bf16 = 4 VGPRs
typedef __attribute__((ext_vector_type(4))) float f32x4;

__device__ __forceinline__ float4 ld4(const float* p) { return *reinterpret_cast<const float4*>(p); }
__device__ __forceinline__ float2 ld2(const float* p) { return *reinterpret_cast<const float2*>(p); }
__device__ __forceinline__ void st4(float* p, const float4 v) { *reinterpret_cast<float4*>(p) = v; }

__device__ __forceinline__ ushort f2bf(float f) {   // fp32 -> bf16 RNE
    unsigned u = __float_as_uint(f);
    return (ushort)((u + 0x7fffu + ((u >> 16) & 1u)) >> 16);
}
__device__ __forceinline__ float bf2f(ushort h) { return __uint_as_float(((unsigned)h) << 16); }

// Activation buffers: [64 rows][128 bf16]. Row stride 256B => swizzle for
// conflict-free A-frag ds_read_b128 (G4).
#define SWZ(row, c) ((row) * 128 + ((c) ^ (((row) & 7) << 3)))

// ---------------- pre-kernel: fp32 weights -> frag-packed bf16 in d_ws ----------------
// Frag chunk = 64 lanes x 16B (8 bf16, consecutive k). Chunk linear index:
//   gcn : (l*4 + ks)*8 + nt                       (64 chunks,  64 KB)
//   W1  : 64  + ((l*4 + p)*4 + ks)*8 + nt         (256 chunks, 256 KB)
//   W2  : 320 + ((l*4 + p)*4 + ks)*8 + nt         (256 chunks, 256 KB)
// B-frag element j of lane: k = kbase + j, n = nt*16 + (lane&15).
__global__ __launch_bounds__(256)
void pack_weights(const float* __restrict__ gcn_W,
                  const float* __restrict__ ffn_W1,
                  const float* __restrict__ ffn_W2,
                  ushort* __restrict__ wsw)
{
    const int t    = blockIdx.x * 256 + threadIdx.x;  // 0..36863
    const int lane = t & 63;
    const int slot = t >> 6;                          // 0..575
    const int grp  = lane >> 4, cl = lane & 15;

    const float* src; int ldn, kbase, n;
    if (slot < 64) {
        const int l = slot >> 5, ks = (slot >> 3) & 3, nt = slot & 7;
        src = gcn_W + l * RR * RR; ldn = RR;
        kbase = ks * 32 + grp * 8;
        n = nt * 16 + cl;
    } else if (slot < 320) {
        const int s = slot - 64;
        const int l = s >> 7, p = (s >> 5) & 3, ks = (s >> 3) & 3, nt = s & 7;
        src = ffn_W1 + l * RR * FF; ldn = FF;
        kbase = ks * 32 + grp * 8;
        n = p * 128 + nt * 16 + cl;
    } else {
        const int s = slot - 320;
        const int l = s >> 7, p = (s >> 5) & 3, ks = (s >> 3) & 3, nt = s & 7;
        src = ffn_W2 + l * FF * RR; ldn = RR;
        kbase = p * 128 + ks * 32 + grp * 8;
        n = nt * 16 + cl;
    }
    ushort v[8];
    #pragma unroll
    for (int j = 0; j < 8; ++j) v[j] = f2bf(src[(size_t)(kbase + j) * ldn + n]);
    uint4 o;
    o.x = v[0] | ((unsigned)v[1] << 16);
    o.y = v[2] | ((unsigned)v[3] << 16);
    o.z = v[4] | ((unsigned)v[5] << 16);
    o.w = v[6] | ((unsigned)v[7] << 16);
    *reinterpret_cast<uint4*>(wsw + ((size_t)slot * 64 + lane) * 8) = o;
}

// frag base (1KB units) of each matmul's 32-frag weight panel
__device__ __forceinline__ int gcnF(int l)        { return l * 32; }
__device__ __forceinline__ int w1F(int l, int p)  { return 64 + (l * 4 + p) * 32; }
__device__ __forceinline__ int w2F(int l, int p)  { return 320 + (l * 4 + p) * 32; }

// Full K=128 matmul for the wave's 32x64 tile, B direct from L2 (d_ws):
// per ki: 2 A ds_read_b128 + 4 coalesced global_load_dwordx4 B-frags, 8 MFMA.
// B-frags register-reused across both 16-row groups. Peak live: T(32)+frags.
#define MMA22G(T, SRCARR, FRAGBASE)                                            \
    {                                                                          \
        const bf16x8* bp_ = wb + (size_t)((FRAGBASE) + ch4) * 64 + lane;       \
        _Pragma("unroll")                                                      \
        for (int ki = 0; ki < 4; ++ki) {                                       \
            const bf16x8 a0_ = *(const bf16x8*)&SRCARR[SWZ(rh32 + cl,          \
                                        ki * 32 + grp * 8)];                   \
            const bf16x8 a1_ = *(const bf16x8*)&SRCARR[SWZ(rh32 + 16 + cl,     \
                                        ki * 32 + grp * 8)];                   \
            _Pragma("unroll")                                                  \
            for (int nt = 0; nt < 4; ++nt) {                                   \
                const bf16x8 b_ = bp_[(ki * 8 + nt) * 64];                     \
                T[nt]     = __builtin_amdgcn_mfma_f32_16x16x32_bf16(a0_, b_, T[nt], 0, 0, 0);     \
                T[4 + nt] = __builtin_amdgcn_mfma_f32_16x16x32_bf16(a1_, b_, T[4 + nt], 0, 0, 0); \
            }                                                                  \
        }                                                                      \
    }

// Half-height variant: 16 rows x 64 cols into T4[4] (used for W1 so acc+t
// are never both 32-wide live; r13's spill fix). B-frags re-loaded per rg.
#define MMA12G(T4, SRCARR, FRAGBASE, ROWB)                                     \
    {                                                                          \
        const bf16x8* bp_ = wb + (size_t)((FRAGBASE) + ch4) * 64 + lane;       \
        _Pragma("unroll")                                                      \
        for (int ki = 0; ki < 4; ++ki) {                                       \
            const bf16x8 a_ = *(const bf16x8*)&SRCARR[SWZ((ROWB) + cl,         \
                                        ki * 32 + grp * 8)];                   \
            _Pragma("unroll")                                                  \
            for (int nt = 0; nt < 4; ++nt) {                                   \
                const bf16x8 b_ = bp_[(ki * 8 + nt) * 64];                     \
                T4[nt] = __builtin_amdgcn_mfma_f32_16x16x32_bf16(a_, b_, T4[nt], 0, 0, 0); \
            }                                                                  \
        }                                                                      \
    }

// ---------------- main kernel: 7 graphs per block, 2x2 wave tiling,
// MFMA 16x16x32 bf16, B from L2, min-waves=3 with W1 rg-split.
// r13: (256,3) alone spilled (VGPR cap 84 < W1-phase demand ~100; WRITE
// 113MB). This round cuts true W1 live-state: t computed 4-frags-at-a-time
// (acc 32 + t4 16 + frags ~20 + addr ~12 ~= 82 <= 84). Occupancy 3/SIMD
// held, spill tripwire: FETCH ~9MB / WRITE ~256KB.
__global__ __launch_bounds__(256, 3)
void backbone_mfma(const float* __restrict__ graph,
                   const int*   __restrict__ op_idx,
                   const float* __restrict__ op_table,
                   const float* __restrict__ dev_embed,
                   const float* __restrict__ gcn_b,
                   const float* __restrict__ ln_g,
                   const float* __restrict__ ln_b,
                   const float* __restrict__ ffn_b1,
                   const float* __restrict__ ffn_b2,
                   const float* __restrict__ fc_w,
                   const float* __restrict__ fc_b,
                   const ushort* __restrict__ wsw,
                   float* __restrict__ out,
                   const int nB)
{
    __shared__ alignas(16) ushort sA[64 * 128];   // x / h_ln (bf16, swizzled)
    __shared__ alignas(16) ushort sGH[64 * 128];  // agg | ffn hidden (disjoint lifetimes)
    __shared__ float sNA[GPB][81];
    __shared__ float sD[ROWS];
    __shared__ float2 sLN[64][2];                 // LN partial sums [row][col-half]
    __shared__ float sRD[64][2];                  // readout partial dots

    const int tid  = threadIdx.x;
    const int lane = tid & 63;
    const int ms   = tid >> 6;        // wave id
    const int grp  = lane >> 4;       // k-group / C row-subgroup
    const int cl   = lane & 15;       // A-row offset / C-col offset
    const int c0   = lane * 2;        // staging/agg column pair
    const int rh32 = (ms >> 1) * 32;  // wave's row base   (2x2 tiling)
    const int ch4  = (ms & 1) * 4;    // wave's B-frag base (col-half * 4)
    const int cb   = ch4 * 16;        // wave's col base (0 or 64)
    const int R0   = ms * 16;         // agg-stage row base
    const int b0   = blockIdx.x * GPB;

    const bf16x8* wb = reinterpret_cast<const bf16x8*>(wsw);

    // zero pad row 63 of both activation buffers
    if (tid < 64) {
        *reinterpret_cast<unsigned*>(&sA[SWZ(63, tid * 2)])  = 0u;
        *reinterpret_cast<unsigned*>(&sGH[SWZ(63, tid * 2)]) = 0u;
    }

    // ---- stage x = op_table[op_idx] + dev_embed  (bf16, swizzled rows) ----
    {
        const float2 dv = ld2(&dev_embed[c0]);
        #pragma unroll
        for (int rr = 0; rr < 16; ++rr) {
            const int row = R0 + rr;
            if (row < ROWS) {
                const int gi = row / NN, ni = row - gi * NN;
                const int gg = min(b0 + gi, nB - 1);
                const int idx = op_idx[gg * NN + ni];       // wave-uniform
                float2 v = ld2(&op_table[idx * RR + c0]);
                unsigned pk = f2bf(v.x + dv.x) | ((unsigned)f2bf(v.y + dv.y) << 16);
                *reinterpret_cast<unsigned*>(&sA[SWZ(row, c0)]) = pk;
            }
        }
    }

    // ---- adjacency normalization (block-strided, 7 graphs) ----
    for (int e = tid; e < GPB * 81; e += 256) {
        const int gi = e / 81, r = e - gi * 81;
        const int i = r / NN, j = r - i * NN;
        const int gg = min(b0 + gi, nB - 1);
        sNA[gi][r] = graph[(size_t)gg * 81 + r] + (i == j ? 1.0f : 0.0f);
    }
    __syncthreads();
    if (tid < ROWS) {
        const int gi = tid / NN, i = tid - gi * NN;
        float s = 0.f;
        #pragma unroll
        for (int j = 0; j < NN; ++j) s += sNA[gi][i * NN + j];
        sD[tid] = rsqrtf(s);
    }
    __syncthreads();
    for (int e = tid; e < GPB * 81; e += 256) {
        const int gi = e / 81, r = e - gi * 81;
        const int i = r / NN, j = r - i * NN;
        sNA[gi][r] *= sD[gi * NN + i] * sD[gi * NN + j];
    }
    __syncthreads();   // x + sNA visible block-wide

    f32x4 acc[8];   // C accumulator [rg*4+nt] (function scope; readout uses it)

    for (int l = 0; l < LL; ++l) {
        // ---- agg = norm_adj @ x -> sGH (wave owns rows R0..R0+16) ----
        {
            const int g0 = R0 / NN, g1 = (R0 + 15) / NN;
            for (int gi = g0; gi <= g1 && gi < GPB; ++gi) {
                float xr[2 * NN];
                #pragma unroll
                for (int j = 0; j < NN; ++j) {
                    unsigned u = *reinterpret_cast<const unsigned*>(&sA[SWZ(gi * NN + j, c0)]);
                    xr[2 * j]     = bf2f((ushort)(u & 0xffffu));
                    xr[2 * j + 1] = bf2f((ushort)(u >> 16));
                }
                const int rlo = max(R0, gi * NN), rhi = min(R0 + 16, gi * NN + NN);
                for (int row = rlo; row < rhi; ++row) {
                    const int ni = row - gi * NN;
                    float a0 = 0.f, a1 = 0.f;
                    #pragma unroll
                    for (int j = 0; j < NN; ++j) {
                        const float w = sNA[gi][ni * NN + j];
                        a0 = fmaf(w, xr[2 * j], a0);
                        a1 = fmaf(w, xr[2 * j + 1], a1);
                    }
                    unsigned pk = f2bf(a0) | ((unsigned)f2bf(a1) << 16);
                    *reinterpret_cast<unsigned*>(&sGH[SWZ(row, c0)]) = pk;
                }
            }
        }
        __syncthreads();   // B1: MFMA A-reads cross wave row boundaries

        // ---- h = agg @ gcn_W via MFMA (B from L2) ----
        #pragma unroll
        for (int i = 0; i < 8; ++i) acc[i] = (f32x4){0.f, 0.f, 0.f, 0.f};
        MMA22G(acc, sGH, gcnF(l));

        // ---- + bias, relu, LN. C: row = rh32+rg*16+grp*4+r, col = cb+nt*16+cl.
        //      Row sums span the two col-half waves -> LDS exchange. ----
        {
            float sv[8] = {0,0,0,0,0,0,0,0}, qv[8] = {0,0,0,0,0,0,0,0};  // [rg*4+r]
            #pragma unroll
            for (int rg = 0; rg < 2; ++rg) {
                #pragma unroll
                for (int nt = 0; nt < 4; ++nt) {
                    const float gb = gcn_b[l * RR + cb + nt * 16 + cl];
                    #pragma unroll
                    for (int r = 0; r < 4; ++r) {
                        float v = fmaxf(acc[rg * 4 + nt][r] + gb, 0.f);
                        acc[rg * 4 + nt][r] = v;
                        sv[rg * 4 + r] += v; qv[rg * 4 + r] += v * v;
                    }
                }
            }
            #pragma unroll
            for (int i = 0; i < 8; ++i) {
                #pragma unroll
                for (int m = 1; m <= 8; m <<= 1) {   // 16-lane row reduce
                    sv[i] += __shfl_xor(sv[i], m);
                    qv[i] += __shfl_xor(qv[i], m);
                }
            }
            if (cl == 0) {
                #pragma unroll
                for (int rg = 0; rg < 2; ++rg)
                    #pragma unroll
                    for (int r = 0; r < 4; ++r)
                        sLN[rh32 + rg * 16 + grp * 4 + r][ms & 1] =
                            make_float2(sv[rg * 4 + r], qv[rg * 4 + r]);
            }
            __syncthreads();   // B2
            float mu[8], rs[8];
            #pragma unroll
            for (int rg = 0; rg < 2; ++rg) {
                #pragma unroll
                for (int r = 0; r < 4; ++r) {
                    const float2 a = sLN[rh32 + rg * 16 + grp * 4 + r][0];
                    const float2 b = sLN[rh32 + rg * 16 + grp * 4 + r][1];
                    const float s = a.x + b.x, q = a.y + b.y;
                    const float m_ = s * (1.f / RR);
                    mu[rg * 4 + r] = m_;
                    rs[rg * 4 + r] = rsqrtf(q * (1.f / RR) - m_ * m_ + 1e-5f);
                }
            }
            #pragma unroll
            for (int rg = 0; rg < 2; ++rg) {
                #pragma unroll
                for (int nt = 0; nt < 4; ++nt) {
                    const float lgv = ln_g[l * RR + cb + nt * 16 + cl];
                    const float lbv = ln_b[l * RR + cb + nt * 16 + cl];
                    #pragma unroll
                    for (int r = 0; r < 4; ++r)
                        acc[rg * 4 + nt][r] = (acc[rg * 4 + nt][r] - mu[rg * 4 + r])
                                              * rs[rg * 4 + r] * lgv + lbv;
                }
            }
        }

        // h_ln -> sA (wave's 32x64 tile)
        #pragma unroll
        for (int rg = 0; rg < 2; ++rg)
            #pragma unroll
            for (int nt = 0; nt < 4; ++nt)
                #pragma unroll
                for (int r = 0; r < 4; ++r)
                    sA[SWZ(rh32 + rg * 16 + grp * 4 + r, cb + nt * 16 + cl)]
                        = f2bf(acc[rg * 4 + nt][r]);
        // acc becomes FFN residual accumulator: acc += ffn_b2
        #pragma unroll
        for (int rg = 0; rg < 2; ++rg)
            #pragma unroll
            for (int nt = 0; nt < 4; ++nt) {
                const float b2v = ffn_b2[l * RR + cb + nt * 16 + cl];
                #pragma unroll
                for (int r = 0; r < 4; ++r) acc[rg * 4 + nt][r] += b2v;
            }
        __syncthreads();   // B3: W1 A-reads are cross-wave

        // ---- FFN: 4 passes over F=512 in 128-wide chunks; W1 rg-split ----
        for (int p = 0; p < 4; ++p) {
            float b1v4[4];
            #pragma unroll
            for (int nt = 0; nt < 4; ++nt)
                b1v4[nt] = ffn_b1[l * FF + p * 128 + cb + nt * 16 + cl];

            {   // rg = 0 half: t4 live only here (16 VGPR)
                f32x4 t0[4];
                #pragma unroll
                for (int nt = 0; nt < 4; ++nt)
                    t0[nt] = (f32x4){b1v4[nt], b1v4[nt], b1v4[nt], b1v4[nt]};
                MMA12G(t0, sA, w1F(l, p), rh32);
                #pragma unroll
                for (int nt = 0; nt < 4; ++nt)
                    #pragma unroll
                    for (int r = 0; r < 4; ++r)
                        sGH[SWZ(rh32 + grp * 4 + r, cb + nt * 16 + cl)]
                            = f2bf(fmaxf(t0[nt][r], 0.f));
            }
            {   // rg = 1 half
                f32x4 t1[4];
                #pragma unroll
                for (int nt = 0; nt < 4; ++nt)
                    t1[nt] = (f32x4){b1v4[nt], b1v4[nt], b1v4[nt], b1v4[nt]};
                MMA12G(t1, sA, w1F(l, p), rh32 + 16);
                #pragma unroll
                for (int nt = 0; nt < 4; ++nt)
                    #pragma unroll
                    for (int r = 0; r < 4; ++r)
                        sGH[SWZ(rh32 + 16 + grp * 4 + r, cb + nt * 16 + cl)]
                            = f2bf(fmaxf(t1[nt][r], 0.f));
            }
            __syncthreads();   // B4: W2 A-reads are cross-wave

            MMA22G(acc, sGH, w2F(l, p));

            if (p < 3) __syncthreads();   // B5: next relu overwrites sGH
        }

        // next-layer x; barrier (next agg reads other waves' rows + sGH rewrite)
        if (l + 1 < LL) {
            #pragma unroll
            for (int rg = 0; rg < 2; ++rg)
                #pragma unroll
                for (int nt = 0; nt < 4; ++nt)
                    #pragma unroll
                    for (int r = 0; r < 4; ++r)
                        sA[SWZ(rh32 + rg * 16 + grp * 4 + r, cb + nt * 16 + cl)]
                            = f2bf(acc[rg * 4 + nt][r]);
            __syncthreads();
        }
    }

    // ---- readout: per-row partial dot (64 cols) -> LDS -> per-graph mean+sigmoid ----
    {
        float p4[8] = {0,0,0,0,0,0,0,0};   // [rg*4+r]
        #pragma unroll
        for (int rg = 0; rg < 2; ++rg)
            #pragma unroll
            for (int nt = 0; nt < 4; ++nt) {
                const float fw = fc_w[cb + nt * 16 + cl];
                #pragma unroll
                for (int r = 0; r < 4; ++r)
                    p4[rg * 4 + r] = fmaf(acc[rg * 4 + nt][r], fw, p4[rg * 4 + r]);
            }
        #pragma unroll
        for (int i = 0; i < 8; ++i) {
            #pragma unroll
            for (int m = 1; m <= 8; m <<= 1) p4[i] += __shfl_xor(p4[i], m);
        }
        if (cl == 0) {
            #pragma unroll
            for (int rg = 0; rg < 2; ++rg)
                #pragma unroll
                for (int r = 0; r < 4; ++r)
                    sRD[rh32 + rg * 16 + grp * 4 + r][ms & 1] = p4[rg * 4 + r];
        }
        __syncthreads();
        if (tid < GPB) {
            const int g = b0 + tid;
            if (g < nB) {
                float s = 0.f;
                #pragma unroll
                for (int n = 0; n < NN; ++n)
                    s += sRD[tid * NN + n][0] + sRD[tid * NN + n][1];
                out[g] = 1.f / (1.f + expf(-(s * (1.f / 9.f) + fc_b[0])));
            }
        }
    }
}

// ---------------- fp32 fallback (round-3 kernel, used if d_ws too small) ----------------
__device__ __forceinline__ void fma4(float4& d, const float a, const float4 w) {
    d.x = fmaf(a, w.x, d.x); d.y = fmaf(a, w.y, d.y);
    d.z = fmaf(a, w.z, d.z); d.w = fmaf(a, w.w, d.w);
}
__device__ __forceinline__ void xadd32(float4& v) {
    v.x += __shfl_xor(v.x, 32); v.y += __shfl_xor(v.y, 32);
    v.z += __shfl_xor(v.z, 32); v.w += __shfl_xor(v.w, 32);
}
__device__ __forceinline__ void relu4f(float4& v) {
    v.x = fmaxf(v.x, 0.f); v.y = fmaxf(v.y, 0.f);
    v.z = fmaxf(v.z, 0.f); v.w = fmaxf(v.w, 0.f);
}

__global__ __launch_bounds__(256)
void backbone_fp32(const float* __restrict__ graph, const int* __restrict__ op_idx,
                   const float* __restrict__ op_table, const float* __restrict__ dev_embed,
                   const float* __restrict__ gcn_W, const float* __restrict__ gcn_b,
                   const float* __restrict__ ln_g, const float* __restrict__ ln_b,
                   const float* __restrict__ ffn_W1, const float* __restrict__ ffn_b1,
                   const float* __restrict__ ffn_W2, const float* __restrict__ ffn_b2,
                   const float* __restrict__ fc_w, const float* __restrict__ fc_b,
                   float* __restrict__ out)
{
    __shared__ float sX[4][NN][RR];
    __shared__ float sT[4][NN][RR];
    __shared__ float sNA[4][81];
    __shared__ float sD[4][NN];

    const int tid  = threadIdx.x;
    const int lane = tid & 63;
    const int cg   = tid & 31;
    const int half = (tid >> 5) & 1;
    const int ms   = tid >> 6;
    const int c0   = cg * 4;
    const int k0   = half * 64;
    const int g    = blockIdx.x * 4 + ms;

    {
        const float dv0 = dev_embed[lane];
        const float dv1 = dev_embed[lane + 64];
        #pragma unroll
        for (int j = 0; j < NN; ++j) {
            const int idx = op_idx[g * NN + j];
            sX[ms][j][lane]      = op_table[idx * RR + lane]      + dv0;
            sX[ms][j][lane + 64] = op_table[idx * RR + lane + 64] + dv1;
        }
    }
    {
        const float* gp = graph + (size_t)g * 81;
        { const int i = lane / NN, j = lane - i * NN;
          sNA[ms][lane] = gp[lane] + (i == j ? 1.0f : 0.0f); }
        if (lane < 17) { const int e = lane + 64; const int i = e / NN, j = e - i * NN;
          sNA[ms][e] = gp[e] + (i == j ? 1.0f : 0.0f); }
        if (lane < NN) {
            float s = 0.f;
            #pragma unroll
            for (int j = 0; j < NN; ++j) s += sNA[ms][lane * NN + j];
            sD[ms][lane] = rsqrtf(s);
        }
        { const int i = lane / NN, j = lane - i * NN; sNA[ms][lane] *= sD[ms][i] * sD[ms][j]; }
        if (lane < 17) { const int e = lane + 64; const int i = e / NN, j = e - i * NN;
          sNA[ms][e] *= sD[ms][i] * sD[ms][j]; }
    }

    float4 acc[NN];
    for (int l = 0; l < LL; ++l) {
        const float* gw = gcn_W  + l * RR * RR;
        const float* gb = gcn_b  + l * RR;
        const float* lg = ln_g   + l * RR;
        const float* lb = ln_b   + l * RR;
        const float* w1 = ffn_W1 + l * RR * FF;
        const float* b1 = ffn_b1 + l * FF;
        const float* w2 = ffn_W2 + l * FF * RR;
        const float* b2 = ffn_b2 + l * RR;
        {
            float4 xv[NN];
            #pragma unroll
            for (int j = 0; j < NN; ++j) xv[j] = ld4(&sX[ms][j][c0]);
            #pragma unroll
            for (int ii = 0; ii < 5; ++ii) {
                const int i = ii + half * 5;
                if (i < NN) {
                    float4 a = make_float4(0.f, 0.f, 0.f, 0.f);
                    #pragma unroll
                    for (int j = 0; j < NN; ++j) fma4(a, sNA[ms][i * NN + j], xv[j]);
                    st4(&sT[ms][i][c0], a);
                }
            }
        }
        float4 h[NN];
        {
            const float4 z4 = make_float4(0.f, 0.f, 0.f, 0.f);
            const float4 gbv = ld4(&gb[c0]);
            const float4 ini = half ? z4 : gbv;
            #pragma unroll
            for (int i = 0; i < NN; ++i) h[i] = ini;
            #pragma unroll 2
            for (int kk = 0; kk < 64; kk += 4) {
                const float* wp = gw + (size_t)(k0 + kk) * RR + c0;
                const float4 wv0 = ld4(wp), wv1 = ld4(wp + RR), wv2 = ld4(wp + 2 * RR), wv3 = ld4(wp + 3 * RR);
                #pragma unroll
                for (int i = 0; i < NN; ++i) {
                    const float4 a = ld4(&sT[ms][i][k0 + kk]);
                    fma4(h[i], a.x, wv0); fma4(h[i], a.y, wv1);
                    fma4(h[i], a.z, wv2); fma4(h[i], a.w, wv3);
                }
            }
            #pragma unroll
            for (int i = 0; i < NN; ++i) xadd32(h[i]);
        }
        {
            const float4 lgv = ld4(&lg[c0]);
            const float4 lbv = ld4(&lb[c0]);
            #pragma unroll
            for (int i = 0; i < NN; ++i) {
                float4 v = h[i]; relu4f(v);
                float s = v.x + v.y + v.z + v.w;
                float q = v.x*v.x + v.y*v.y + v.z*v.z + v.w*v.w;
                #pragma unroll
                for (int m = 1; m <= 16; m <<= 1) { s += __shfl_xor(s, m); q += __shfl_xor(q, m); }
                const float mu = s * (1.f / RR);
                const float var = q * (1.f / RR) - mu * mu;
                const float rs = rsqrtf(var + 1e-5f);
                v.x = (v.x - mu) * rs * lgv.x + lbv.x;
                v.y = (v.y - mu) * rs * lgv.y + lbv.y;
                v.z = (v.z - mu) * rs * lgv.z + lbv.z;
                v.w = (v.w - mu) * rs * lgv.w + lbv.w;
                h[i] = v;
            }
        }
        #pragma unroll
        for (int i = 0; i < NN; ++i) st4(&sX[ms][i][c0], h[i]);
        {
            const float4 b2v = ld4(&b2[c0]);
            #pragma unroll
            for (int i = 0; i < NN; ++i) {
                if (half) acc[i] = make_float4(0.f, 0.f, 0.f, 0.f);
                else { acc[i] = h[i];
                       acc[i].x += b2v.x; acc[i].y += b2v.y; acc[i].z += b2v.z; acc[i].w += b2v.w; }
            }
        }
        for (int p = 0; p < 4; ++p) {
            const int f0 = p * RR + c0;
            float4 t[NN];
            {
                const float4 z4 = make_float4(0.f, 0.f, 0.f, 0.f);
                const float4 b1v = ld4(&b1[f0]);
                const float4 ini = half ? z4 : b1v;
                #pragma unroll
                for (int i = 0; i < NN; ++i) t[i] = ini;
            }
            #pragma unroll 2
            for (int kk = 0; kk < 64; kk += 4) {
                const float* wp = w1 + (size_t)(k0 + kk) * FF + f0;
                const float4 wv0 = ld4(wp), wv1 = ld4(wp + FF), wv2 = ld4(wp + 2 * FF), wv3 = ld4(wp + 3 * FF);
                #pragma unroll
                for (int i = 0; i < NN; ++i) {
                    const float4 a = ld4(&sX[ms][i][k0 + kk]);
                    fma4(t[i], a.x, wv0); fma4(t[i], a.y, wv1);
                    fma4(t[i], a.z, wv2); fma4(t[i], a.w, wv3);
                }
            }
            #pragma unroll
            for (int i = 0; i < NN; ++i) { xadd32(t[i]); relu4f(t[i]); st4(&sT[ms][i][c0], t[i]); }
            #pragma unroll 2
            for (int kk = 0; kk < 64; kk += 4) {
                const float* wp = w2 + (size_t)(p * RR + k0 + kk) * RR + c0;
                const float4 wv0 = ld4(wp), wv1 = ld4(wp + RR), wv2 = ld4(wp + 2 * RR), wv3 = ld4(wp + 3 * RR);
                #pragma unroll
                for (int i = 0; i < NN; ++i) {
                    const float4 a = ld4(&sT[ms][i][k0 + kk]);
                    fma4(acc[i], a.x, wv0); fma4(acc[i], a.y, wv1);
                    fma4(acc[i], a.z, wv2); fma4(acc[i], a.w, wv3);
                }
            }
        }
        #pragma unroll
        for (int i = 0; i < NN; ++i) xadd32(acc[i]);
        if (l + 1 < LL) {
            #pragma unroll
            for (int i = 0; i < NN; ++i) st4(&sX[ms][i][c0], acc[i]);
        }
    }
    {
        const float4 fw = ld4(&fc_w[c0]);
        float4 pv = make_float4(0.f, 0.f, 0.f, 0.f);
        #pragma unroll
        for (int i = 0; i < NN; ++i) { pv.x += acc[i].x; pv.y += acc[i].y; pv.z += acc[i].z; pv.w += acc[i].w; }
        float part = (pv.x*fw.x + pv.y*fw.y + pv.z*fw.z + pv.w*fw.w) * (1.f / 9.f);
        #pragma unroll
        for (int m = 1; m <= 16; m <<= 1) part += __shfl_xor(part, m);
        if (lane == 0) out[g] = 1.f / (1.f + expf(-(part + fc_b[0])));
    }
}

extern "C" void kernel_launch(void* const* d_in, const int* in_sizes, int n_in,
                              void* d_out, int out_size, void* d_ws, size_t ws_size,
                              hipStream_t stream) {
    const float* graph     = (const float*)d_in[0];
    const int*   op_idx    = (const int*)  d_in[1];
    const float* op_table  = (const float*)d_in[2];
    const float* dev_embed = (const float*)d_in[3];
    const float* gcn_W     = (const float*)d_in[4];
    const float* gcn_b     = (const float*)d_in[5];
    const float* ln_g      = (const float*)d_in[6];
    const float* ln_b      = (const float*)d_in[7];
    const float* ffn_W1    = (const float*)d_in[8];
    const float* ffn_b1    = (const float*)d_in[9];
    const float* ffn_W2    = (const float*)d_in[10];
    const float* ffn_b2    = (const float*)d_in[11];
    const float* fc_w      = (const float*)d_in[12];
    const float* fc_b      = (const float*)d_in[13];
    float* out = (float*)d_out;

    const int nB = in_sizes[0] / 81;          // 32768
    const size_t WS_NEED = 576 * 1024;        // frag-packed bf16 weights

    if (d_ws != nullptr && ws_size >= WS_NEED) {
        pack_weights<<<dim3(144), dim3(256), 0, stream>>>(gcn_W, ffn_W1, ffn_W2, (ushort*)d_ws);
        backbone_mfma<<<dim3((nB + GPB - 1) / GPB), dim3(256), 0, stream>>>(
            graph, op_idx, op_table, dev_embed, gcn_b, ln_g, ln_b,
            ffn_b1, ffn_b2, fc_w, fc_b, (const ushort*)d_ws, out, nB);
    } else {
        backbone_fp32<<<dim3(nB / 4), dim3(256), 0, stream>>>(
            graph, op_idx, op_table, dev_embed, gcn_W, gcn_b, ln_g, ln_b,
            ffn_W1, ffn_b1, ffn_W2, ffn_b2, fc_w, fc_b, out);
    }
}

// Round 15
// 384.332 us; speedup vs baseline: 1.2974x; 1.2974x over previous
//
#include <hip/hip_runtime.h>
#include <math.h>

#define NN 9
#define RR 128
#define FF 512
#define LL 2
#define GPB 7      // graphs per block (4 waves x 16 rows = 64 rows; 63 used)
#define ROWS 63

typedef __attribute__((ext_vector_type(8))) short bf16x8;  // 8 bf16 = 4 VGPRs
typedef __attribute__((ext_vector_type(4))) float f32x4;

__device__ __forceinline__ float4 ld4(const float* p) { return *reinterpret_cast<const float4*>(p); }
__device__ __forceinline__ float2 ld2(const float* p) { return *reinterpret_cast<const float2*>(p); }
__device__ __forceinline__ void st4(float* p, const float4 v) { *reinterpret_cast<float4*>(p) = v; }

__device__ __forceinline__ ushort f2bf(float f) {   // fp32 -> bf16 RNE
    unsigned u = __float_as_uint(f);
    return (ushort)((u + 0x7fffu + ((u >> 16) & 1u)) >> 16);
}
__device__ __forceinline__ float bf2f(ushort h) { return __uint_as_float(((unsigned)h) << 16); }

// async global->LDS, 16B per lane. LDS dest = wave-uniform base + lane*16 (HW);
// global src is per-lane. Size must be a literal.
__device__ __forceinline__ void async16(void* lds, const void* g) {
    __builtin_amdgcn_global_load_lds(
        (const __attribute__((address_space(1))) unsigned int*)g,
        (__attribute__((address_space(3))) unsigned int*)lds,
        16, 0, 0);
}

// Activation buffers: [64 rows][128 bf16] (global row space for the 7 graphs).
// Row stride 256B => swizzle for conflict-free A-frag ds_read_b128 (G4).
#define SWZ(row, c) ((row) * 128 + ((c) ^ (((row) & 7) << 3)))

// ---------------- pre-kernel: fp32 weights -> frag-packed bf16 in d_ws ----------------
// Frag chunk = 64 lanes x 16B (8 bf16, consecutive k). Chunk linear index:
//   gcn : (l*4 + ks)*8 + nt                       (64 chunks,  64 KB)
//   W1  : 64  + ((l*4 + p)*4 + ks)*8 + nt         (256 chunks, 256 KB)
//   W2  : 320 + ((l*4 + p)*4 + ks)*8 + nt         (256 chunks, 256 KB)
// B-frag element j of lane: k = kbase + j, n = nt*16 + (lane&15).
__global__ __launch_bounds__(256)
void pack_weights(const float* __restrict__ gcn_W,
                  const float* __restrict__ ffn_W1,
                  const float* __restrict__ ffn_W2,
                  ushort* __restrict__ wsw)
{
    const int t    = blockIdx.x * 256 + threadIdx.x;  // 0..36863
    const int lane = t & 63;
    const int slot = t >> 6;                          // 0..575
    const int grp  = lane >> 4, cl = lane & 15;

    const float* src; int ldn, kbase, n;
    if (slot < 64) {
        const int l = slot >> 5, ks = (slot >> 3) & 3, nt = slot & 7;
        src = gcn_W + l * RR * RR; ldn = RR;
        kbase = ks * 32 + grp * 8;
        n = nt * 16 + cl;
    } else if (slot < 320) {
        const int s = slot - 64;
        const int l = s >> 7, p = (s >> 5) & 3, ks = (s >> 3) & 3, nt = s & 7;
        src = ffn_W1 + l * RR * FF; ldn = FF;
        kbase = ks * 32 + grp * 8;
        n = p * 128 + nt * 16 + cl;
    } else {
        const int s = slot - 320;
        const int l = s >> 7, p = (s >> 5) & 3, ks = (s >> 3) & 3, nt = s & 7;
        src = ffn_W2 + l * FF * RR; ldn = RR;
        kbase = p * 128 + ks * 32 + grp * 8;
        n = nt * 16 + cl;
    }
    ushort v[8];
    #pragma unroll
    for (int j = 0; j < 8; ++j) v[j] = f2bf(src[(size_t)(kbase + j) * ldn + n]);
    uint4 o;
    o.x = v[0] | ((unsigned)v[1] << 16);
    o.y = v[2] | ((unsigned)v[3] << 16);
    o.z = v[4] | ((unsigned)v[5] << 16);
    o.w = v[6] | ((unsigned)v[7] << 16);
    *reinterpret_cast<uint4*>(wsw + ((size_t)slot * 64 + lane) * 8) = o;
}

// 16-frag (16 KB) group base helpers, in 1KB-frag units. kh in {0,1} selects
// ks-pair {0,1} or {2,3}.
__device__ __forceinline__ int g16(int l, int kh)         { return (l * 4 + kh * 2) * 8; }
__device__ __forceinline__ int w1g(int l, int p, int kh)  { return 64 + ((l * 4 + p) * 4 + kh * 2) * 8; }
__device__ __forceinline__ int w2g(int l, int p, int kh)  { return 320 + ((l * 4 + p) * 4 + kh * 2) * 8; }

// consume one staged 16-frag group: 2 A-frags, 16 ds_read_b128 B-frags, 16 MFMA
#define MMA_GROUP2(T, APTR0, APTR1, BUFSEL)                                    \
    {                                                                          \
        const unsigned char* bb_ = &wbuf[BUFSEL][lane << 4];                   \
        const bf16x8 af0_ = *(const bf16x8*)(APTR0);                           \
        _Pragma("unroll")                                                      \
        for (int nt = 0; nt < 8; ++nt)                                         \
            T[nt] = __builtin_amdgcn_mfma_f32_16x16x32_bf16(                   \
                af0_, *(const bf16x8*)(bb_ + (nt << 10)), T[nt], 0, 0, 0);     \
        const bf16x8 af1_ = *(const bf16x8*)(APTR1);                           \
        _Pragma("unroll")                                                      \
        for (int nt = 0; nt < 8; ++nt)                                         \
            T[nt] = __builtin_amdgcn_mfma_f32_16x16x32_bf16(                   \
                af1_, *(const bf16x8*)(bb_ + ((8 + nt) << 10)), T[nt], 0, 0, 0); \
    }

// stage the 16-frag group FRAGBASE into wbuf[DST]: each wave stages 4 frags
#define STAGE16(DST, FRAGBASE)                                                 \
    {                                                                          \
        const unsigned char* g_ = wsb + ((size_t)((FRAGBASE) + ms * 4) << 10)  \
                                      + (lane << 4);                           \
        async16(&wbuf[DST][(ms * 4 + 0) << 10], g_);                           \
        async16(&wbuf[DST][(ms * 4 + 1) << 10], g_ + 1024);                    \
        async16(&wbuf[DST][(ms * 4 + 2) << 10], g_ + 2048);                    \
        async16(&wbuf[DST][(ms * 4 + 3) << 10], g_ + 3072);                    \
    }

// ---------------- main kernel: 4 waves x 16 M-rows = 7 graphs per block,
// MFMA 16x16x32 bf16, block-shared double-buffered 16KB weight staging ----
// (r10 configuration — best verified: 385.1us. r11 B-reuse neutral, r12
// L2-direct neutral, r13/r14 min-waves=3 spilled. 2 waves/SIMD is the
// hardware's answer at ~100 VGPR true demand; structural plateau.)
__global__ __launch_bounds__(256, 2)
void backbone_mfma(const float* __restrict__ graph,
                   const int*   __restrict__ op_idx,
                   const float* __restrict__ op_table,
                   const float* __restrict__ dev_embed,
                   const float* __restrict__ gcn_b,
                   const float* __restrict__ ln_g,
                   const float* __restrict__ ln_b,
                   const float* __restrict__ ffn_b1,
                   const float* __restrict__ ffn_b2,
                   const float* __restrict__ fc_w,
                   const float* __restrict__ fc_b,
                   const ushort* __restrict__ wsw,
                   float* __restrict__ out,
                   const int nB)
{
    __shared__ alignas(16) ushort sA[64 * 128];   // x / h_ln (bf16, swizzled)
    __shared__ alignas(16) ushort sGH[64 * 128];  // agg | ffn hidden (disjoint lifetimes)
    __shared__ float sNA[GPB][81];
    __shared__ float sD[ROWS];
    __shared__ float sRD[64];                     // per-row readout dots
    __shared__ alignas(16) unsigned char wbuf[2][16384];  // 16KB weight double buffer

    const int tid  = threadIdx.x;
    const int lane = tid & 63;
    const int ms   = tid >> 6;        // wave id: owns global rows [16*ms, 16*ms+16)
    const int grp  = lane >> 4;       // k-group for MFMA frags / C row-group
    const int cl   = lane & 15;       // A-row (local) / C-col
    const int c0   = lane * 2;        // this lane's 2 cols for staging/agg
    const int R0   = ms * 16;
    const int b0   = blockIdx.x * GPB;

    const unsigned char* wsb = (const unsigned char*)wsw;

    // zero pad row 63 of both activation buffers
    if (tid < 64) {
        *reinterpret_cast<unsigned*>(&sA[SWZ(63, tid * 2)])  = 0u;
        *reinterpret_cast<unsigned*>(&sGH[SWZ(63, tid * 2)]) = 0u;
    }

    // ---- stage x = op_table[op_idx] + dev_embed  (bf16, swizzled rows) ----
    {
        const float2 dv = ld2(&dev_embed[c0]);
        #pragma unroll
        for (int rr = 0; rr < 16; ++rr) {
            const int row = R0 + rr;
            if (row < ROWS) {
                const int gi = row / NN, ni = row - gi * NN;
                const int gg = min(b0 + gi, nB - 1);
                const int idx = op_idx[gg * NN + ni];       // wave-uniform
                float2 v = ld2(&op_table[idx * RR + c0]);
                unsigned pk = f2bf(v.x + dv.x) | ((unsigned)f2bf(v.y + dv.y) << 16);
                *reinterpret_cast<unsigned*>(&sA[SWZ(row, c0)]) = pk;
            }
        }
    }

    // ---- adjacency normalization (block-strided, 7 graphs) ----
    for (int e = tid; e < GPB * 81; e += 256) {
        const int gi = e / 81, r = e - gi * 81;
        const int i = r / NN, j = r - i * NN;
        const int gg = min(b0 + gi, nB - 1);
        sNA[gi][r] = graph[(size_t)gg * 81 + r] + (i == j ? 1.0f : 0.0f);
    }
    __syncthreads();
    if (tid < ROWS) {
        const int gi = tid / NN, i = tid - gi * NN;
        float s = 0.f;
        #pragma unroll
        for (int j = 0; j < NN; ++j) s += sNA[gi][i * NN + j];
        sD[tid] = rsqrtf(s);
    }
    __syncthreads();
    for (int e = tid; e < GPB * 81; e += 256) {
        const int gi = e / 81, r = e - gi * 81;
        const int i = r / NN, j = r - i * NN;
        sNA[gi][r] *= sD[gi * NN + i] * sD[gi * NN + j];
    }

    // prologue: stage first weight group; full-drain sync (x, sNA visible;
    // group 0 in LDS)
    int cur = 0;
    STAGE16(0, g16(0, 0));
    __syncthreads();

    f32x4 acc[8];   // MFMA C-layout accumulator (function scope; readout uses it)

    for (int l = 0; l < LL; ++l) {
        // ---- agg = norm_adj @ x -> sGH, wave's rows grouped by graph ----
        {
            const int g0 = R0 / NN, g1 = (R0 + 15) / NN;
            for (int gi = g0; gi <= g1 && gi < GPB; ++gi) {
                float xr[2 * NN];
                #pragma unroll
                for (int j = 0; j < NN; ++j) {
                    unsigned u = *reinterpret_cast<const unsigned*>(&sA[SWZ(gi * NN + j, c0)]);
                    xr[2 * j]     = bf2f((ushort)(u & 0xffffu));
                    xr[2 * j + 1] = bf2f((ushort)(u >> 16));
                }
                const int rlo = max(R0, gi * NN), rhi = min(R0 + 16, gi * NN + NN);
                for (int row = rlo; row < rhi; ++row) {
                    const int ni = row - gi * NN;
                    float a0 = 0.f, a1 = 0.f;
                    #pragma unroll
                    for (int j = 0; j < NN; ++j) {
                        const float w = sNA[gi][ni * NN + j];
                        a0 = fmaf(w, xr[2 * j], a0);
                        a1 = fmaf(w, xr[2 * j + 1], a1);
                    }
                    unsigned pk = f2bf(a0) | ((unsigned)f2bf(a1) << 16);
                    *reinterpret_cast<unsigned*>(&sGH[SWZ(row, c0)]) = pk;
                }
            }
        }

        // ---- h = agg @ gcn_W via MFMA (2 staged 16KB phases) ----
        #pragma unroll
        for (int nt = 0; nt < 8; ++nt) acc[nt] = (f32x4){0.f, 0.f, 0.f, 0.f};
        #pragma unroll
        for (int kh = 0; kh < 2; ++kh) {
            const int nb = (kh == 0) ? g16(l, 1) : w1g(l, 0, 0);
            STAGE16(cur ^ 1, nb);
            MMA_GROUP2(acc,
                       &sGH[SWZ(R0 + cl, (kh * 2 + 0) * 32 + grp * 8)],
                       &sGH[SWZ(R0 + cl, (kh * 2 + 1) * 32 + grp * 8)], cur);
            __syncthreads();
            cur ^= 1;
        }

        // ---- + bias, relu, layernorm (C: col = nt*16+cl, row = R0+grp*4+r) ----
        {
            float sv[4] = {0.f, 0.f, 0.f, 0.f}, qv[4] = {0.f, 0.f, 0.f, 0.f};
            #pragma unroll
            for (int nt = 0; nt < 8; ++nt) {
                const float gb = gcn_b[l * RR + nt * 16 + cl];
                #pragma unroll
                for (int r = 0; r < 4; ++r) {
                    float v = fmaxf(acc[nt][r] + gb, 0.f);
                    acc[nt][r] = v;
                    sv[r] += v; qv[r] += v * v;
                }
            }
            #pragma unroll
            for (int r = 0; r < 4; ++r) {
                #pragma unroll
                for (int m = 1; m <= 8; m <<= 1) {   // row lives in a 16-lane group
                    sv[r] += __shfl_xor(sv[r], m);
                    qv[r] += __shfl_xor(qv[r], m);
                }
            }
            float mu[4], rs[4];
            #pragma unroll
            for (int r = 0; r < 4; ++r) {
                mu[r] = sv[r] * (1.f / RR);
                const float var = qv[r] * (1.f / RR) - mu[r] * mu[r];
                rs[r] = rsqrtf(var + 1e-5f);
            }
            #pragma unroll
            for (int nt = 0; nt < 8; ++nt) {
                const float lgv = ln_g[l * RR + nt * 16 + cl];
                const float lbv = ln_b[l * RR + nt * 16 + cl];
                #pragma unroll
                for (int r = 0; r < 4; ++r)
                    acc[nt][r] = (acc[nt][r] - mu[r]) * rs[r] * lgv + lbv;
            }
        }

        // h_ln -> sA (own rows; row 63 garbage is finite & never consumed)
        #pragma unroll
        for (int nt = 0; nt < 8; ++nt) {
            #pragma unroll
            for (int r = 0; r < 4; ++r)
                sA[SWZ(R0 + grp * 4 + r, nt * 16 + cl)] = f2bf(acc[nt][r]);
        }
        // acc becomes the FFN residual accumulator in place: acc += ffn_b2
        #pragma unroll
        for (int nt = 0; nt < 8; ++nt) {
            const float b2v = ffn_b2[l * RR + nt * 16 + cl];
            #pragma unroll
            for (int r = 0; r < 4; ++r) acc[nt][r] += b2v;
        }

        // ---- FFN: 4 passes over F=512 in 128-wide chunks ----
        for (int p = 0; p < 4; ++p) {
            f32x4 t[8];
            #pragma unroll
            for (int nt = 0; nt < 8; ++nt) {
                const float b1v = ffn_b1[l * FF + p * 128 + nt * 16 + cl];
                t[nt] = (f32x4){b1v, b1v, b1v, b1v};
            }
            #pragma unroll
            for (int kh = 0; kh < 2; ++kh) {
                const int nb = (kh == 0) ? w1g(l, p, 1) : w2g(l, p, 0);
                STAGE16(cur ^ 1, nb);
                MMA_GROUP2(t,
                           &sA[SWZ(R0 + cl, (kh * 2 + 0) * 32 + grp * 8)],
                           &sA[SWZ(R0 + cl, (kh * 2 + 1) * 32 + grp * 8)], cur);
                __syncthreads();
                cur ^= 1;
            }
            // relu -> hidden chunk to sGH (own rows; in-wave write->read order)
            #pragma unroll
            for (int nt = 0; nt < 8; ++nt) {
                #pragma unroll
                for (int r = 0; r < 4; ++r)
                    sGH[SWZ(R0 + grp * 4 + r, nt * 16 + cl)] = f2bf(fmaxf(t[nt][r], 0.f));
            }
            #pragma unroll
            for (int kh = 0; kh < 2; ++kh) {
                const bool last = (l == LL - 1) && (p == 3) && (kh == 1);
                const int nb = (kh == 0) ? w2g(l, p, 1)
                             : ((p < 3) ? w1g(l, p + 1, 0) : g16(l + 1, 0));
                if (!last) STAGE16(cur ^ 1, nb);
                MMA_GROUP2(acc,
                           &sGH[SWZ(R0 + cl, (kh * 2 + 0) * 32 + grp * 8)],
                           &sGH[SWZ(R0 + cl, (kh * 2 + 1) * 32 + grp * 8)], cur);
                __syncthreads();
                cur ^= 1;
            }
        }

        // next-layer x; sync: next agg reads other waves' rows
        if (l + 1 < LL) {
            #pragma unroll
            for (int nt = 0; nt < 8; ++nt) {
                #pragma unroll
                for (int r = 0; r < 4; ++r)
                    sA[SWZ(R0 + grp * 4 + r, nt * 16 + cl)] = f2bf(acc[nt][r]);
            }
            __syncthreads();
        }
    }

    // ---- readout: per-row dot (16-lane reduce) -> LDS -> per-graph mean+sigmoid ----
    {
        float p4[4] = {0.f, 0.f, 0.f, 0.f};
        #pragma unroll
        for (int nt = 0; nt < 8; ++nt) {
            const float fw = fc_w[nt * 16 + cl];
            #pragma unroll
            for (int r = 0; r < 4; ++r) p4[r] = fmaf(acc[nt][r], fw, p4[r]);
        }
        #pragma unroll
        for (int r = 0; r < 4; ++r) {
            #pragma unroll
            for (int m = 1; m <= 8; m <<= 1) p4[r] += __shfl_xor(p4[r], m);
        }
        if (cl == 0) {
            #pragma unroll
            for (int r = 0; r < 4; ++r) sRD[R0 + grp * 4 + r] = p4[r];
        }
        __syncthreads();
        if (tid < GPB) {
            const int g = b0 + tid;
            if (g < nB) {
                float s = 0.f;
                #pragma unroll
                for (int n = 0; n < NN; ++n) s += sRD[tid * NN + n];
                out[g] = 1.f / (1.f + expf(-(s * (1.f / 9.f) + fc_b[0])));
            }
        }
    }
}

// ---------------- fp32 fallback (round-3 kernel, used if d_ws too small) ----------------
__device__ __forceinline__ void fma4(float4& d, const float a, const float4 w) {
    d.x = fmaf(a, w.x, d.x); d.y = fmaf(a, w.y, d.y);
    d.z = fmaf(a, w.z, d.z); d.w = fmaf(a, w.w, d.w);
}
__device__ __forceinline__ void xadd32(float4& v) {
    v.x += __shfl_xor(v.x, 32); v.y += __shfl_xor(v.y, 32);
    v.z += __shfl_xor(v.z, 32); v.w += __shfl_xor(v.w, 32);
}
__device__ __forceinline__ void relu4f(float4& v) {
    v.x = fmaxf(v.x, 0.f); v.y = fmaxf(v.y, 0.f);
    v.z = fmaxf(v.z, 0.f); v.w = fmaxf(v.w, 0.f);
}

__global__ __launch_bounds__(256)
void backbone_fp32(const float* __restrict__ graph, const int* __restrict__ op_idx,
                   const float* __restrict__ op_table, const float* __restrict__ dev_embed,
                   const float* __restrict__ gcn_W, const float* __restrict__ gcn_b,
                   const float* __restrict__ ln_g, const float* __restrict__ ln_b,
                   const float* __restrict__ ffn_W1, const float* __restrict__ ffn_b1,
                   const float* __restrict__ ffn_W2, const float* __restrict__ ffn_b2,
                   const float* __restrict__ fc_w, const float* __restrict__ fc_b,
                   float* __restrict__ out)
{
    __shared__ float sX[4][NN][RR];
    __shared__ float sT[4][NN][RR];
    __shared__ float sNA[4][81];
    __shared__ float sD[4][NN];

    const int tid  = threadIdx.x;
    const int lane = tid & 63;
    const int cg   = tid & 31;
    const int half = (tid >> 5) & 1;
    const int ms   = tid >> 6;
    const int c0   = cg * 4;
    const int k0   = half * 64;
    const int g    = blockIdx.x * 4 + ms;

    {
        const float dv0 = dev_embed[lane];
        const float dv1 = dev_embed[lane + 64];
        #pragma unroll
        for (int j = 0; j < NN; ++j) {
            const int idx = op_idx[g * NN + j];
            sX[ms][j][lane]      = op_table[idx * RR + lane]      + dv0;
            sX[ms][j][lane + 64] = op_table[idx * RR + lane + 64] + dv1;
        }
    }
    {
        const float* gp = graph + (size_t)g * 81;
        { const int i = lane / NN, j = lane - i * NN;
          sNA[ms][lane] = gp[lane] + (i == j ? 1.0f : 0.0f); }
        if (lane < 17) { const int e = lane + 64; const int i = e / NN, j = e - i * NN;
          sNA[ms][e] = gp[e] + (i == j ? 1.0f : 0.0f); }
        if (lane < NN) {
            float s = 0.f;
            #pragma unroll
            for (int j = 0; j < NN; ++j) s += sNA[ms][lane * NN + j];
            sD[ms][lane] = rsqrtf(s);
        }
        { const int i = lane / NN, j = lane - i * NN; sNA[ms][lane] *= sD[ms][i] * sD[ms][j]; }
        if (lane < 17) { const int e = lane + 64; const int i = e / NN, j = e - i * NN;
          sNA[ms][e] *= sD[ms][i] * sD[ms][j]; }
    }

    float4 acc[NN];
    for (int l = 0; l < LL; ++l) {
        const float* gw = gcn_W  + l * RR * RR;
        const float* gb = gcn_b  + l * RR;
        const float* lg = ln_g   + l * RR;
        const float* lb = ln_b   + l * RR;
        const float* w1 = ffn_W1 + l * RR * FF;
        const float* b1 = ffn_b1 + l * FF;
        const float* w2 = ffn_W2 + l * FF * RR;
        const float* b2 = ffn_b2 + l * RR;
        {
            float4 xv[NN];
            #pragma unroll
            for (int j = 0; j < NN; ++j) xv[j] = ld4(&sX[ms][j][c0]);
            #pragma unroll
            for (int ii = 0; ii < 5; ++ii) {
                const int i = ii + half * 5;
                if (i < NN) {
                    float4 a = make_float4(0.f, 0.f, 0.f, 0.f);
                    #pragma unroll
                    for (int j = 0; j < NN; ++j) fma4(a, sNA[ms][i * NN + j], xv[j]);
                    st4(&sT[ms][i][c0], a);
                }
            }
        }
        float4 h[NN];
        {
            const float4 z4 = make_float4(0.f, 0.f, 0.f, 0.f);
            const float4 gbv = ld4(&gb[c0]);
            const float4 ini = half ? z4 : gbv;
            #pragma unroll
            for (int i = 0; i < NN; ++i) h[i] = ini;
            #pragma unroll 2
            for (int kk = 0; kk < 64; kk += 4) {
                const float* wp = gw + (size_t)(k0 + kk) * RR + c0;
                const float4 wv0 = ld4(wp), wv1 = ld4(wp + RR), wv2 = ld4(wp + 2 * RR), wv3 = ld4(wp + 3 * RR);
                #pragma unroll
                for (int i = 0; i < NN; ++i) {
                    const float4 a = ld4(&sT[ms][i][k0 + kk]);
                    fma4(h[i], a.x, wv0); fma4(h[i], a.y, wv1);
                    fma4(h[i], a.z, wv2); fma4(h[i], a.w, wv3);
                }
            }
            #pragma unroll
            for (int i = 0; i < NN; ++i) xadd32(h[i]);
        }
        {
            const float4 lgv = ld4(&lg[c0]);
            const float4 lbv = ld4(&lb[c0]);
            #pragma unroll
            for (int i = 0; i < NN; ++i) {
                float4 v = h[i]; relu4f(v);
                float s = v.x + v.y + v.z + v.w;
                float q = v.x*v.x + v.y*v.y + v.z*v.z + v.w*v.w;
                #pragma unroll
                for (int m = 1; m <= 16; m <<= 1) { s += __shfl_xor(s, m); q += __shfl_xor(q, m); }
                const float mu = s * (1.f / RR);
                const float var = q * (1.f / RR) - mu * mu;
                const float rs = rsqrtf(var + 1e-5f);
                v.x = (v.x - mu) * rs * lgv.x + lbv.x;
                v.y = (v.y - mu) * rs * lgv.y + lbv.y;
                v.z = (v.z - mu) * rs * lgv.z + lbv.z;
                v.w = (v.w - mu) * rs * lgv.w + lbv.w;
                h[i] = v;
            }
        }
        #pragma unroll
        for (int i = 0; i < NN; ++i) st4(&sX[ms][i][c0], h[i]);
        {
            const float4 b2v = ld4(&b2[c0]);
            #pragma unroll
            for (int i = 0; i < NN; ++i) {
                if (half) acc[i] = make_float4(0.f, 0.f, 0.f, 0.f);
                else { acc[i] = h[i];
                       acc[i].x += b2v.x; acc[i].y += b2v.y; acc[i].z += b2v.z; acc[i].w += b2v.w; }
            }
        }
        for (int p = 0; p < 4; ++p) {
            const int f0 = p * RR + c0;
            float4 t[NN];
            {
                const float4 z4 = make_float4(0.f, 0.f, 0.f, 0.f);
                const float4 b1v = ld4(&b1[f0]);
                const float4 ini = half ? z4 : b1v;
                #pragma unroll
                for (int i = 0; i < NN; ++i) t[i] = ini;
            }
            #pragma unroll 2
            for (int kk = 0; kk < 64; kk += 4) {
                const float* wp = w1 + (size_t)(k0 + kk) * FF + f0;
                const float4 wv0 = ld4(wp), wv1 = ld4(wp + FF), wv2 = ld4(wp + 2 * FF), wv3 = ld4(wp + 3 * FF);
                #pragma unroll
                for (int i = 0; i < NN; ++i) {
                    const float4 a = ld4(&sX[ms][i][k0 + kk]);
                    fma4(t[i], a.x, wv0); fma4(t[i], a.y, wv1);
                    fma4(t[i], a.z, wv2); fma4(t[i], a.w, wv3);
                }
            }
            #pragma unroll
            for (int i = 0; i < NN; ++i) { xadd32(t[i]); relu4f(t[i]); st4(&sT[ms][i][c0], t[i]); }
            #pragma unroll 2
            for (int kk = 0; kk < 64; kk += 4) {
                const float* wp = w2 + (size_t)(p * RR + k0 + kk) * RR + c0;
                const float4 wv0 = ld4(wp), wv1 = ld4(wp + RR), wv2 = ld4(wp + 2 * RR), wv3 = ld4(wp + 3 * RR);
                #pragma unroll
                for (int i = 0; i < NN; ++i) {
                    const float4 a = ld4(&sT[ms][i][k0 + kk]);
                    fma4(acc[i], a.x, wv0); fma4(acc[i], a.y, wv1);
                    fma4(acc[i], a.z, wv2); fma4(acc[i], a.w, wv3);
                }
            }
        }
        #pragma unroll
        for (int i = 0; i < NN; ++i) xadd32(acc[i]);
        if (l + 1 < LL) {
            #pragma unroll
            for (int i = 0; i < NN; ++i) st4(&sX[ms][i][c0], acc[i]);
        }
    }
    {
        const float4 fw = ld4(&fc_w[c0]);
        float4 pv = make_float4(0.f, 0.f, 0.f, 0.f);
        #pragma unroll
        for (int i = 0; i < NN; ++i) { pv.x += acc[i].x; pv.y += acc[i].y; pv.z += acc[i].z; pv.w += acc[i].w; }
        float part = (pv.x*fw.x + pv.y*fw.y + pv.z*fw.z + pv.w*fw.w) * (1.f / 9.f);
        #pragma unroll
        for (int m = 1; m <= 16; m <<= 1) part += __shfl_xor(part, m);
        if (lane == 0) out[g] = 1.f / (1.f + expf(-(part + fc_b[0])));
    }
}

extern "C" void kernel_launch(void* const* d_in, const int* in_sizes, int n_in,
                              void* d_out, int out_size, void* d_ws, size_t ws_size,
                              hipStream_t stream) {
    const float* graph     = (const float*)d_in[0];
    const int*   op_idx    = (const int*)  d_in[1];
    const float* op_table  = (const float*)d_in[2];
    const float* dev_embed = (const float*)d_in[3];
    const float* gcn_W     = (const float*)d_in[4];
    const float* gcn_b     = (const float*)d_in[5];
    const float* ln_g      = (const float*)d_in[6];
    const float* ln_b      = (const float*)d_in[7];
    const float* ffn_W1    = (const float*)d_in[8];
    const float* ffn_b1    = (const float*)d_in[9];
    const float* ffn_W2    = (const float*)d_in[10];
    const float* ffn_b2    = (const float*)d_in[11];
    const float* fc_w      = (const float*)d_in[12];
    const float* fc_b      = (const float*)d_in[13];
    float* out = (float*)d_out;

    const int nB = in_sizes[0] / 81;          // 32768
    const size_t WS_NEED = 576 * 1024;        // frag-packed bf16 weights

    if (d_ws != nullptr && ws_size >= WS_NEED) {
        pack_weights<<<dim3(144), dim3(256), 0, stream>>>(gcn_W, ffn_W1, ffn_W2, (ushort*)d_ws);
        backbone_mfma<<<dim3((nB + GPB - 1) / GPB), dim3(256), 0, stream>>>(
            graph, op_idx, op_table, dev_embed, gcn_b, ln_g, ln_b,
            ffn_b1, ffn_b2, fc_w, fc_b, (const ushort*)d_ws, out, nB);
    } else {
        backbone_fp32<<<dim3(nB / 4), dim3(256), 0, stream>>>(
            graph, op_idx, op_table, dev_embed, gcn_W, gcn_b, ln_g, ln_b,
            ffn_W1, ffn_b1, ffn_W2, ffn_b2, fc_w, fc_b, out);
    }
}